// Round 13
// baseline (139.253 us; speedup 1.0000x reference)
//
#include <hip/hip_runtime.h>
#include <cstdint>
#include <cstddef>

using u32 = unsigned int;
using u64 = unsigned long long;

typedef int v4i  __attribute__((ext_vector_type(4)));
typedef int v16i __attribute__((ext_vector_type(16)));

#define EPSV 1e-5f

// ---------------------------------------------------------------------------
// Kernel 1: weight prep (unchanged). Wsgn[conv][co][p][c] = sign(w - mean);
// SC4 = (alpha, scale, shift, 0), IEEE ops in the reference's exact order.
// ---------------------------------------------------------------------------
__global__ void prep_weights(const float* __restrict__ w1, const float* __restrict__ w2,
                             const float* __restrict__ a1, const float* __restrict__ g1,
                             const float* __restrict__ b1, const float* __restrict__ m1,
                             const float* __restrict__ v1,
                             const float* __restrict__ a2, const float* __restrict__ g2,
                             const float* __restrict__ b2, const float* __restrict__ m2,
                             const float* __restrict__ v2,
                             unsigned char* __restrict__ Wsgn, float4* __restrict__ SC4)
{
    const int co   = blockIdx.x;
    const int conv = blockIdx.y;
    const int c    = threadIdx.x;
    const float* w = conv ? w2 : w1;

    float wv[9];
    const float* wp = w + ((size_t)co * 256 + c) * 9;
    float s = 0.f;
#pragma unroll
    for (int p = 0; p < 9; ++p) { wv[p] = wp[p]; s += wv[p]; }

    __shared__ float red[256];
    red[c] = s;
    __syncthreads();
    for (int off = 128; off > 0; off >>= 1) {
        if (c < off) red[c] += red[c + off];
        __syncthreads();
    }
    const float mean = __fdiv_rn(red[0], 2304.0f);

    unsigned char* wrow = Wsgn + ((size_t)(conv * 256 + co) * 9) * 256;
#pragma unroll
    for (int p = 0; p < 9; ++p)
        wrow[p * 256 + c] = (wv[p] > mean) ? 0x01u : 0xFFu;

    if (c == 0) {
        const float alpha = conv ? a2[co] : a1[co];
        const float gamma = conv ? g2[co] : g1[co];
        const float beta  = conv ? b2[co] : b1[co];
        const float mu    = conv ? m2[co] : m1[co];
        const float var   = conv ? v2[co] : v1[co];
        const float sq    = __fsqrt_rn(__fadd_rn(var, EPSV));
        const float scale = __fdiv_rn(gamma, sq);
        const float shift = __fsub_rn(beta, __fdiv_rn(__fmul_rn(mu, gamma), sq));
        SC4[conv * 256 + co] = make_float4(alpha, scale, shift, 0.f);
    }
}

// ---------------------------------------------------------------------------
// Kernel 2: B fragments in exact mfma_i32_32x32x32_i8 operand order.
// Frag f = conv*576 + g*72 + k (k = p*8+cb). Lane l: B[k=(l>>5)*16+j][n=l&31].
// ---------------------------------------------------------------------------
__global__ void build_bfrag(const unsigned char* __restrict__ Wsgn, uint4* __restrict__ Bf)
{
    const int f    = blockIdx.x;           // 0..1151
    const int lane = threadIdx.x;          // 0..63
    const int conv = f / 576;
    const int rem  = f % 576;
    const int g    = rem / 72;
    const int p    = (rem % 72) / 8;
    const int cb   = rem % 8;
    const int co   = g * 32 + (lane & 31);
    const unsigned char* src = Wsgn + ((size_t)(conv * 256 + co) * 9 + p) * 256
                                    + cb * 32 + (lane >> 5) * 16;
    Bf[(size_t)f * 64 + lane] = *(const uint4*)src;
}

// ---------------------------------------------------------------------------
// Kernel 3: binarize x -> packed bits. A[n][pixel][j], j = chan/32.
// ---------------------------------------------------------------------------
__global__ void binarize_x(const float* __restrict__ x, u32* __restrict__ A1)
{
    const int n = blockIdx.x >> 3;
    const int j = blockIdx.x & 7;
    const int p = threadIdx.x;
    const float* xp = x + (((size_t)n * 256 + j * 32) * 1024) + p;
    u32 bits = 0;
#pragma unroll
    for (int k = 0; k < 32; ++k) {
        float v = xp[(size_t)k * 1024];
        bits |= (v > 0.f ? 1u : 0u) << k;
    }
    A1[((size_t)n * 1024 + p) * 8 + j] = bits;
}

__device__ __forceinline__ u32 expand4(u32 x)
{
    u32 r;
    r  = ((x & 1u) ? 0x00000001u : 0x000000FFu);
    r |= ((x & 2u) ? 0x00000100u : 0x0000FF00u);
    r |= ((x & 4u) ? 0x00010000u : 0x00FF0000u);
    r |= ((x & 8u) ? 0x01000000u : 0xFF000000u);
    return r;
}

__device__ __forceinline__ void glds16(const void* g, void* l)
{
    __builtin_amdgcn_global_load_lds(
        (const __attribute__((address_space(1))) void*)g,
        (__attribute__((address_space(3))) void*)l, 16, 0, 0);
}

// ---------------------------------------------------------------------------
// Kernel 4/5: binary conv as i8 MFMA GEMM — async-LDS-B version.
// R12 lesson: per-lane GLOBAL B loads put an L2 round trip on every step's
// critical path; 4 schedules all plateaued at MfmaUtil 22-25%. Fix: B is
// staged into LDS with global_load_lds (async, no dest regs). Steady-state
// K-loop touches only LDS; the vm drain rides the per-step __syncthreads,
// which ~600 cyc of MFMA+ds_read have already covered (m97 pattern).
//
// Block: 256 thr = 4 waves; M=128 (4 rows x 32 cols of one image), N=256.
// Wave (wm=w>>1, wn=w&1): rows y0+2wm..+1, groups wn*4..+3 -> 8 v16i accs.
// Grid 512 = 2 blocks/CU; LDS exactly 65,536 B:
//   [0,16384): B dbuf  (buf b at b*8192; group g at g*1024; +lane*16)
//   [16384,65536): A tile [c16 16][row 6][xs 32] 16B cells — NO column halo;
//     edge columns use clamped address + zero-mask (padding contributes 0).
// Per k-step: wave issues 2 glds for step k+1 |SB|, 2 A + 4 B ds_read_b128,
// setprio(1), 8 MFMA, setprio(0), __syncthreads.
// Pipe math per CU-step: LDS ~704 cyc vs matrix ~585 -> ceiling ~83%.
//
// A: m(=x)=l&31, k=(l>>5)*16+j ; B: n(=co)=l&31 ; C/D: n=l&31,
// m=(reg&3)+8*(reg>>2)+4*(l>>5)   [R5-R12 HW-verified].
//
// CONV==1: t=(dot*alpha)*scale+shift; packed sign bits via __ballot.
// CONV==2: per-row LDS transpose ep[x][co] (pad 257) -> coalesced
//          clamp(t + X) float4 stores.
// ---------------------------------------------------------------------------
template<int CONV>
__global__ __launch_bounds__(256, 2)
void conv_mfma(const u32* __restrict__ A_in, const v4i* __restrict__ Bf,
               const float4* __restrict__ SC4, const float* __restrict__ X,
               u32* __restrict__ A_out, float* __restrict__ OUT)
{
    const int n    = blockIdx.x >> 3;
    const int yq   = blockIdx.x & 7;
    const int y0   = yq * 4;
    const int tid  = threadIdx.x;
    const int wave = tid >> 6;
    const int lane = tid & 63;
    const int wm   = wave >> 1;          // row-pair: y0+2wm, y0+2wm+1
    const int wn   = wave & 1;           // co-half: groups wn*4..wn*4+3
    const int col0 = lane & 31;

    __shared__ alignas(16) unsigned char lds[65536];

    const int fbias = (CONV == 2) ? 576 : 0;
    const char* bsrc0 = (const char*)Bf
        + (((size_t)(fbias + wave * 2 * 72)) << 10) + (size_t)lane * 16;

    // prologue: stage step-0 B into buf 0 (async, overlaps A staging)
    glds16(bsrc0,              lds + wave * 2048);
    glds16(bsrc0 + (72 << 10), lds + wave * 2048 + 1024);

    // stage A tile: rows y0-1..y0+4, cols 0..31, 256 ch -> i8 (row halo -> 0)
    for (int s = tid; s < 3072; s += 256) {
        const int xs   = s & 31;
        const int rest = s >> 5;
        const int r    = rest % 6;
        const int c16  = rest / 6;
        const int iy   = y0 - 1 + r;
        u32 d0 = 0, d1 = 0, d2 = 0, d3 = 0;
        if ((unsigned)iy < 32u) {
            const u32 wrd = A_in[((size_t)n * 1024 + iy * 32 + xs) * 8 + (c16 >> 1)];
            const u32 h = (wrd >> ((c16 & 1) * 16)) & 0xFFFFu;
            d0 = expand4(h);
            d1 = expand4(h >> 4);
            d2 = expand4(h >> 8);
            d3 = expand4(h >> 12);
        }
        *(uint4*)(lds + 16384 + (size_t)s * 16) = make_uint4(d0, d1, d2, d3);
    }
    __syncthreads();   // A staged; B step-0 glds drained

    const v16i Z  = {0,0,0,0,0,0,0,0,0,0,0,0,0,0,0,0};
    const v4i  Z4 = {0,0,0,0};
    v16i c00 = Z, c01 = Z, c02 = Z, c03 = Z;   // row y0+2wm   x ni=0..3
    v16i c10 = Z, c11 = Z, c12 = Z, c13 = Z;   // row y0+2wm+1 x ni=0..3

    const u32 abase = 16384u + (u32)((lane >> 5) * 3072 + wm * 1024);
    const u32 bbase = (u32)(wn * 4096 + lane * 16);

#pragma unroll 1
    for (int k = 0; k < 72; ++k) {
        {   // stage step k+1 -> buf (k+1)&1 (wrap harmlessly re-stages 0)
            int kn = k + 1; if (kn == 72) kn = 0;
            const char* s0 = bsrc0 + ((size_t)kn << 10);
            unsigned char* d = lds + (kn & 1) * 8192 + wave * 2048;
            glds16(s0, d);
            glds16(s0 + (72 << 10), d + 1024);
        }
        __builtin_amdgcn_sched_barrier(0);

        const int p  = k >> 3, cb = k & 7;
        const int dy = p / 3,  dx = p - dy * 3;
        int c = col0 + dx - 1; c = c < 0 ? 0 : (c > 31 ? 31 : c);
        const u32 ao = abase + (u32)(cb * 6144 + dy * 512 + c * 16);
        v4i a0 = *(const v4i*)(lds + ao);
        v4i a1 = *(const v4i*)(lds + ao + 512);
        const bool kill = (dx == 0 && col0 == 0) || (dx == 2 && col0 == 31);
        if (kill) { a0 = Z4; a1 = Z4; }

        const u32 bo = bbase + (u32)((k & 1) * 8192);
        const v4i b0 = *(const v4i*)(lds + bo);
        const v4i b1 = *(const v4i*)(lds + bo + 1024);
        const v4i b2 = *(const v4i*)(lds + bo + 2048);
        const v4i b3 = *(const v4i*)(lds + bo + 3072);

        __builtin_amdgcn_s_setprio(1);
        c00 = __builtin_amdgcn_mfma_i32_32x32x32_i8(a0, b0, c00, 0, 0, 0);
        c01 = __builtin_amdgcn_mfma_i32_32x32x32_i8(a0, b1, c01, 0, 0, 0);
        c02 = __builtin_amdgcn_mfma_i32_32x32x32_i8(a0, b2, c02, 0, 0, 0);
        c03 = __builtin_amdgcn_mfma_i32_32x32x32_i8(a0, b3, c03, 0, 0, 0);
        c10 = __builtin_amdgcn_mfma_i32_32x32x32_i8(a1, b0, c10, 0, 0, 0);
        c11 = __builtin_amdgcn_mfma_i32_32x32x32_i8(a1, b1, c11, 0, 0, 0);
        c12 = __builtin_amdgcn_mfma_i32_32x32x32_i8(a1, b2, c12, 0, 0, 0);
        c13 = __builtin_amdgcn_mfma_i32_32x32x32_i8(a1, b3, c13, 0, 0, 0);
        __builtin_amdgcn_s_setprio(0);

        __syncthreads();   // staged k+1 drained (covered) + buf read done
    }

    const int bias2 = (CONV == 2) ? 256 : 0;
    const float4 sc0 = SC4[bias2 + (wn * 4 + 0) * 32 + col0];
    const float4 sc1 = SC4[bias2 + (wn * 4 + 1) * 32 + col0];
    const float4 sc2 = SC4[bias2 + (wn * 4 + 2) * 32 + col0];
    const float4 sc3 = SC4[bias2 + (wn * 4 + 3) * 32 + col0];

    if (CONV == 1) {
#define EP1(ACC, MI, NI, SC)                                                    \
        { _Pragma("unroll")                                                     \
          for (int reg = 0; reg < 16; ++reg) {                                  \
              const float t = __fadd_rn(__fmul_rn(__fmul_rn((float)ACC[reg],    \
                                        SC.x), SC.y), SC.z);                    \
              const u64 m = __ballot(t > 0.f);                                  \
              if (lane == 0) {                                                  \
                  const int x = (reg & 3) + 8 * (reg >> 2);                     \
                  const int row = y0 + 2 * wm + (MI);                           \
                  const size_t pb = (size_t)n * 1024 + row * 32 + x;            \
                  A_out[pb * 8 + (wn * 4 + (NI))]       = (u32)m;               \
                  A_out[(pb + 4) * 8 + (wn * 4 + (NI))] = (u32)(m >> 32);       \
              } } }
        EP1(c00, 0, 0, sc0)  EP1(c01, 0, 1, sc1)
        EP1(c02, 0, 2, sc2)  EP1(c03, 0, 3, sc3)
        EP1(c10, 1, 0, sc0)  EP1(c11, 1, 1, sc1)
        EP1(c12, 1, 2, sc2)  EP1(c13, 1, 3, sc3)
#undef EP1
    } else {
        __syncthreads();
        float* ep = (float*)lds;            // ep[x][co], stride 257 (32.9 KB)
#define EP2PASS(C0, C1, C2, C3, R)                                              \
        { if (wm == ((R) >> 1)) {                                               \
            _Pragma("unroll")                                                   \
            for (int reg = 0; reg < 16; ++reg) {                                \
                const int x = (reg & 3) + 8 * (reg >> 2) + 4 * (lane >> 5);     \
                ep[x * 257 + (wn * 4 + 0) * 32 + col0] =                        \
                    __fadd_rn(__fmul_rn(__fmul_rn((float)C0[reg], sc0.x),       \
                                        sc0.y), sc0.z);                         \
                ep[x * 257 + (wn * 4 + 1) * 32 + col0] =                        \
                    __fadd_rn(__fmul_rn(__fmul_rn((float)C1[reg], sc1.x),       \
                                        sc1.y), sc1.z);                         \
                ep[x * 257 + (wn * 4 + 2) * 32 + col0] =                        \
                    __fadd_rn(__fmul_rn(__fmul_rn((float)C2[reg], sc2.x),       \
                                        sc2.y), sc2.z);                         \
                ep[x * 257 + (wn * 4 + 3) * 32 + col0] =                        \
                    __fadd_rn(__fmul_rn(__fmul_rn((float)C3[reg], sc3.x),       \
                                        sc3.y), sc3.z);                         \
            } }                                                                 \
          __syncthreads();                                                      \
          {                                                                     \
              const int co = tid;                                               \
              const size_t gb = ((size_t)(n * 256 + co)) * 1024                 \
                              + (y0 + (R)) * 32;                                \
              _Pragma("unroll")                                                 \
              for (int x4 = 0; x4 < 32; x4 += 4) {                              \
                  float4 r;                                                     \
                  r.x = ep[(x4 + 0) * 257 + co];                                \
                  r.y = ep[(x4 + 1) * 257 + co];                                \
                  r.z = ep[(x4 + 2) * 257 + co];                                \
                  r.w = ep[(x4 + 3) * 257 + co];                                \
                  const float4 xv = *(const float4*)(X + gb + x4);              \
                  r.x = fminf(1.f, fmaxf(-1.f, __fadd_rn(r.x, xv.x)));          \
                  r.y = fminf(1.f, fmaxf(-1.f, __fadd_rn(r.y, xv.y)));          \
                  r.z = fminf(1.f, fmaxf(-1.f, __fadd_rn(r.z, xv.z)));          \
                  r.w = fminf(1.f, fmaxf(-1.f, __fadd_rn(r.w, xv.w)));          \
                  *(float4*)(OUT + gb + x4) = r;                                \
              }                                                                 \
          }                                                                     \
          __syncthreads(); }
        EP2PASS(c00, c01, c02, c03, 0)
        EP2PASS(c10, c11, c12, c13, 1)
        EP2PASS(c00, c01, c02, c03, 2)
        EP2PASS(c10, c11, c12, c13, 3)
#undef EP2PASS
    }
}

// ---------------------------------------------------------------------------
extern "C" void kernel_launch(void* const* d_in, const int* in_sizes, int n_in,
                              void* d_out, int out_size, void* d_ws, size_t ws_size,
                              hipStream_t stream)
{
    const float* x   = (const float*)d_in[0];
    const float* w1  = (const float*)d_in[1];
    const float* al1 = (const float*)d_in[2];
    const float* g1  = (const float*)d_in[3];
    const float* b1  = (const float*)d_in[4];
    const float* m1  = (const float*)d_in[5];
    const float* v1  = (const float*)d_in[6];
    const float* w2  = (const float*)d_in[7];
    const float* al2 = (const float*)d_in[8];
    const float* g2  = (const float*)d_in[9];
    const float* b2  = (const float*)d_in[10];
    const float* m2  = (const float*)d_in[11];
    const float* v2  = (const float*)d_in[12];
    float* out = (float*)d_out;

    char* ws = (char*)d_ws;
    float4*        SC4  = (float4*)(ws);                        //   8 KB
    unsigned char* Wsgn = (unsigned char*)(ws + (64u << 10));   // 1.18 MB
    uint4*         Bf   = (uint4*)(ws + (2u << 20));            // 1.18 MB
    u32*           A1   = (u32*)(ws + (4u << 20));              // 2 MB
    u32*           A2   = (u32*)(ws + (6u << 20));              // 2 MB
    (void)ws_size; (void)in_sizes; (void)n_in; (void)out_size;

    prep_weights<<<dim3(256, 2), 256, 0, stream>>>(w1, w2, al1, g1, b1, m1, v1,
                                                   al2, g2, b2, m2, v2, Wsgn, SC4);
    build_bfrag<<<dim3(1152), 64, 0, stream>>>(Wsgn, Bf);
    binarize_x<<<dim3(512), 1024, 0, stream>>>(x, A1);
    conv_mfma<1><<<dim3(512), 256, 0, stream>>>(A1, (const v4i*)Bf, SC4,
                                                nullptr, A2, nullptr);
    conv_mfma<2><<<dim3(512), 256, 0, stream>>>(A2, (const v4i*)Bf, SC4,
                                                x, nullptr, out);
}

// Round 14
// 138.569 us; speedup vs baseline: 1.0049x; 1.0049x over previous
//
#include <hip/hip_runtime.h>
#include <cstdint>
#include <cstddef>

using u32 = unsigned int;
using u64 = unsigned long long;

typedef int v4i  __attribute__((ext_vector_type(4)));
typedef int v16i __attribute__((ext_vector_type(16)));

#define EPSV 1e-5f

// ---------------------------------------------------------------------------
// Kernel 1: weight prep (unchanged). Wsgn[conv][co][p][c] = sign(w - mean);
// SC4 = (alpha, scale, shift, 0), IEEE ops in the reference's exact order.
// ---------------------------------------------------------------------------
__global__ void prep_weights(const float* __restrict__ w1, const float* __restrict__ w2,
                             const float* __restrict__ a1, const float* __restrict__ g1,
                             const float* __restrict__ b1, const float* __restrict__ m1,
                             const float* __restrict__ v1,
                             const float* __restrict__ a2, const float* __restrict__ g2,
                             const float* __restrict__ b2, const float* __restrict__ m2,
                             const float* __restrict__ v2,
                             unsigned char* __restrict__ Wsgn, float4* __restrict__ SC4)
{
    const int co   = blockIdx.x;
    const int conv = blockIdx.y;
    const int c    = threadIdx.x;
    const float* w = conv ? w2 : w1;

    float wv[9];
    const float* wp = w + ((size_t)co * 256 + c) * 9;
    float s = 0.f;
#pragma unroll
    for (int p = 0; p < 9; ++p) { wv[p] = wp[p]; s += wv[p]; }

    __shared__ float red[256];
    red[c] = s;
    __syncthreads();
    for (int off = 128; off > 0; off >>= 1) {
        if (c < off) red[c] += red[c + off];
        __syncthreads();
    }
    const float mean = __fdiv_rn(red[0], 2304.0f);

    unsigned char* wrow = Wsgn + ((size_t)(conv * 256 + co) * 9) * 256;
#pragma unroll
    for (int p = 0; p < 9; ++p)
        wrow[p * 256 + c] = (wv[p] > mean) ? 0x01u : 0xFFu;

    if (c == 0) {
        const float alpha = conv ? a2[co] : a1[co];
        const float gamma = conv ? g2[co] : g1[co];
        const float beta  = conv ? b2[co] : b1[co];
        const float mu    = conv ? m2[co] : m1[co];
        const float var   = conv ? v2[co] : v1[co];
        const float sq    = __fsqrt_rn(__fadd_rn(var, EPSV));
        const float scale = __fdiv_rn(gamma, sq);
        const float shift = __fsub_rn(beta, __fdiv_rn(__fmul_rn(mu, gamma), sq));
        SC4[conv * 256 + co] = make_float4(alpha, scale, shift, 0.f);
    }
}

// ---------------------------------------------------------------------------
// Kernel 2: B fragments in exact mfma_i32_32x32x32_i8 operand order.
// Frag f = conv*576 + g*72 + k (k = p*8+cb). Lane l: B[k=(l>>5)*16+j][n=l&31].
// ---------------------------------------------------------------------------
__global__ void build_bfrag(const unsigned char* __restrict__ Wsgn, uint4* __restrict__ Bf)
{
    const int f    = blockIdx.x;           // 0..1151
    const int lane = threadIdx.x;          // 0..63
    const int conv = f / 576;
    const int rem  = f % 576;
    const int g    = rem / 72;
    const int p    = (rem % 72) / 8;
    const int cb   = rem % 8;
    const int co   = g * 32 + (lane & 31);
    const unsigned char* src = Wsgn + ((size_t)(conv * 256 + co) * 9 + p) * 256
                                    + cb * 32 + (lane >> 5) * 16;
    Bf[(size_t)f * 64 + lane] = *(const uint4*)src;
}

// ---------------------------------------------------------------------------
// Kernel 3: binarize x -> packed bits. A[n][pixel][j], j = chan/32.
// ---------------------------------------------------------------------------
__global__ void binarize_x(const float* __restrict__ x, u32* __restrict__ A1)
{
    const int n = blockIdx.x >> 3;
    const int j = blockIdx.x & 7;
    const int p = threadIdx.x;
    const float* xp = x + (((size_t)n * 256 + j * 32) * 1024) + p;
    u32 bits = 0;
#pragma unroll
    for (int k = 0; k < 32; ++k) {
        float v = xp[(size_t)k * 1024];
        bits |= (v > 0.f ? 1u : 0u) << k;
    }
    A1[((size_t)n * 1024 + p) * 8 + j] = bits;
}

__device__ __forceinline__ u32 expand4(u32 x)
{
    u32 r;
    r  = ((x & 1u) ? 0x00000001u : 0x000000FFu);
    r |= ((x & 2u) ? 0x00000100u : 0x0000FF00u);
    r |= ((x & 4u) ? 0x00010000u : 0x00FF0000u);
    r |= ((x & 8u) ? 0x01000000u : 0xFF000000u);
    return r;
}

__device__ __forceinline__ void glds16(const void* g, void* l)
{
    __builtin_amdgcn_global_load_lds(
        (const __attribute__((address_space(1))) void*)g,
        (__attribute__((address_space(3))) void*)l, 16, 0, 0);
}

// ---------------------------------------------------------------------------
// Kernel 4/5: binary conv as i8 MFMA GEMM — BARRIER-FREE K-loop.
// R13 lesson: the per-step __syncthreads emits s_waitcnt vmcnt(0), draining
// the just-issued prefetch -> full L2 latency per step, MfmaUtil stuck ~21%
// across 5 schedule variants. Fix: make B staging WAVE-PRIVATE so the K-loop
// needs no barrier at all:
//   wave w owns co-groups 2w,2w+1 for ALL 4 output rows (8 accs);
//   B ring: 4 slots x 2KB per wave in LDS, filled 3 steps ahead via
//   global_load_lds; consumed after inline-asm s_waitcnt vmcnt(6) (counted,
//   never 0 — T4). A tile (48KB) staged once, read-only, one barrier.
//   Waves drift freely -> no lockstep L2 bursts; loads have ~3 steps
//   (~1000cyc) of cover. Slot-reuse safe: a slot's ds_read completes
//   (lgkm-waited before its MFMA) before the overwriting glds issues.
//
// Block: 256 thr = 4 waves; M=128 (4 rows x 32 cols), N=256. Grid 512 =
// 2 blocks/CU (LDS exactly 81,920 B = A 48K + B rings 32K + pad).
// LDS A tile [c16 16][row 6][col 32] 16B cells at 0; offs = c16*3072 +
// row*512 + col*16. No column halo: edge cols use clamped addr + zero-mask.
// B ring at 49152 + wave*8192 + slot*2048 (+1024 for group g1).
//
// A: m(=x)=l&31, k=(l>>5)*16+j ; B: n(=co)=l&31 ; C/D: n=l&31,
// m=(reg&3)+8*(reg>>2)+4*(l>>5)   [R5-R13 HW-verified].
//
// CONV==1: t=(dot*alpha)*scale+shift; packed sign bits via __ballot.
// CONV==2: per-row LDS transpose ep[x][co] (pad 257) -> coalesced
//          clamp(t + X) float4 stores.
// ---------------------------------------------------------------------------
template<int CONV>
__global__ __launch_bounds__(256, 2)
void conv_mfma(const u32* __restrict__ A_in, const v4i* __restrict__ Bf,
               const float4* __restrict__ SC4, const float* __restrict__ X,
               u32* __restrict__ A_out, float* __restrict__ OUT)
{
    const int n    = blockIdx.x >> 3;
    const int yq   = blockIdx.x & 7;
    const int y0   = yq * 4;
    const int tid  = threadIdx.x;
    const int wave = tid >> 6;
    const int lane = tid & 63;
    const int col0 = lane & 31;

    __shared__ alignas(16) unsigned char lds[81920];

    const int fbias = (CONV == 2) ? 576 : 0;
    const int g0 = wave * 2;
    const char* bsrc0 = (const char*)Bf + (((size_t)(fbias + g0 * 72)) << 10)
                        + (size_t)lane * 16;
    unsigned char* bslot = lds + 49152 + wave * 8192;

    // prologue: stage B pairs 0,1,2 into slots 0,1,2 (async)
#pragma unroll
    for (int i = 0; i < 3; ++i) {
        glds16(bsrc0 + ((size_t)i << 10), bslot + i * 2048);
        glds16(bsrc0 + ((size_t)i << 10) + 73728, bslot + i * 2048 + 1024);
    }

    // stage A tile: rows y0-1..y0+4, cols 0..31, 256 ch -> i8 (row halo -> 0)
    for (int s = tid; s < 3072; s += 256) {
        const int xs   = s & 31;
        const int rest = s >> 5;
        const int r    = rest % 6;
        const int c16  = rest / 6;
        const int iy   = y0 - 1 + r;
        u32 d0 = 0, d1 = 0, d2 = 0, d3 = 0;
        if ((unsigned)iy < 32u) {
            const u32 wrd = A_in[((size_t)n * 1024 + iy * 32 + xs) * 8 + (c16 >> 1)];
            const u32 h = (wrd >> ((c16 & 1) * 16)) & 0xFFFFu;
            d0 = expand4(h);
            d1 = expand4(h >> 4);
            d2 = expand4(h >> 8);
            d3 = expand4(h >> 12);
        }
        *(uint4*)(lds + (size_t)s * 16) = make_uint4(d0, d1, d2, d3);
    }
    __syncthreads();   // A tile visible to all; prologue B drained too

    const v16i Z  = {0,0,0,0,0,0,0,0,0,0,0,0,0,0,0,0};
    const v4i  Z4 = {0,0,0,0};
    v16i c0a = Z, c0b = Z;   // row y0+0 x {g0, g0+1}
    v16i c1a = Z, c1b = Z;   // row y0+1
    v16i c2a = Z, c2b = Z;   // row y0+2
    v16i c3a = Z, c3b = Z;   // row y0+3

    const u32 bb = 49152u + (u32)(wave * 8192 + lane * 16);

#pragma unroll 1
    for (int k = 0; k < 72; ++k) {
        // issue B pair k+3 -> slot (k+3)&3 (wrap source harmlessly)
        {
            const int kf  = k + 3;
            const int kfm = (kf >= 72) ? kf - 72 : kf;
            const char* s0 = bsrc0 + ((size_t)kfm << 10);
            unsigned char* d = bslot + (kf & 3) * 2048;
            glds16(s0, d);
            glds16(s0 + 73728, d + 1024);
        }
        __builtin_amdgcn_sched_barrier(0);

        const int p  = k >> 3, cb = k & 7;
        const int dy = p / 3,  dx = p - dy * 3;
        int c = col0 + dx - 1; c = c < 0 ? 0 : (c > 31 ? 31 : c);
        const u32 ao = (u32)((lane >> 5) * 3072 + cb * 6144 + dy * 512 + c * 16);
        v4i a0 = *(const v4i*)(lds + ao);
        v4i a1 = *(const v4i*)(lds + ao + 512);
        v4i a2 = *(const v4i*)(lds + ao + 1024);
        v4i a3 = *(const v4i*)(lds + ao + 1536);
        if ((dx == 0 && col0 == 0) || (dx == 2 && col0 == 31)) {
            a0 = Z4; a1 = Z4; a2 = Z4; a3 = Z4;
        }

        // counted wait: pair k complete (pairs k+1..k+3 = 6 ops stay in flight)
        asm volatile("s_waitcnt vmcnt(6)" ::: "memory");
        __builtin_amdgcn_sched_barrier(0);

        const u32 bo = bb + (u32)((k & 3) * 2048);
        const v4i b0 = *(const v4i*)(lds + bo);
        const v4i b1 = *(const v4i*)(lds + bo + 1024);

        __builtin_amdgcn_s_setprio(1);
        c0a = __builtin_amdgcn_mfma_i32_32x32x32_i8(a0, b0, c0a, 0, 0, 0);
        c0b = __builtin_amdgcn_mfma_i32_32x32x32_i8(a0, b1, c0b, 0, 0, 0);
        c1a = __builtin_amdgcn_mfma_i32_32x32x32_i8(a1, b0, c1a, 0, 0, 0);
        c1b = __builtin_amdgcn_mfma_i32_32x32x32_i8(a1, b1, c1b, 0, 0, 0);
        c2a = __builtin_amdgcn_mfma_i32_32x32x32_i8(a2, b0, c2a, 0, 0, 0);
        c2b = __builtin_amdgcn_mfma_i32_32x32x32_i8(a2, b1, c2b, 0, 0, 0);
        c3a = __builtin_amdgcn_mfma_i32_32x32x32_i8(a3, b0, c3a, 0, 0, 0);
        c3b = __builtin_amdgcn_mfma_i32_32x32x32_i8(a3, b1, c3b, 0, 0, 0);
        __builtin_amdgcn_s_setprio(0);
    }

    const int bias2 = (CONV == 2) ? 256 : 0;
    const float4 scA = SC4[bias2 + (g0 + 0) * 32 + col0];
    const float4 scB = SC4[bias2 + (g0 + 1) * 32 + col0];

    if (CONV == 1) {
#define EP1(ACC, R, G, SC)                                                      \
        { _Pragma("unroll")                                                     \
          for (int reg = 0; reg < 16; ++reg) {                                  \
              const float t = __fadd_rn(__fmul_rn(__fmul_rn((float)ACC[reg],    \
                                        SC.x), SC.y), SC.z);                    \
              const u64 m = __ballot(t > 0.f);                                  \
              if (lane == 0) {                                                  \
                  const int x = (reg & 3) + 8 * (reg >> 2);                     \
                  const size_t pb = (size_t)n * 1024 + (y0 + (R)) * 32 + x;     \
                  A_out[pb * 8 + (G)]       = (u32)m;                           \
                  A_out[(pb + 4) * 8 + (G)] = (u32)(m >> 32);                   \
              } } }
        EP1(c0a, 0, g0, scA)      EP1(c0b, 0, g0 + 1, scB)
        EP1(c1a, 1, g0, scA)      EP1(c1b, 1, g0 + 1, scB)
        EP1(c2a, 2, g0, scA)      EP1(c2b, 2, g0 + 1, scB)
        EP1(c3a, 3, g0, scA)      EP1(c3b, 3, g0 + 1, scB)
#undef EP1
    } else {
        __syncthreads();                    // all waves done with A/B reads
        float* ep = (float*)lds;            // ep[x][co], stride 257 (32.9 KB)
#define EP2PASS(CA, CB, R)                                                      \
        { _Pragma("unroll")                                                     \
          for (int reg = 0; reg < 16; ++reg) {                                  \
              const int x = (reg & 3) + 8 * (reg >> 2) + 4 * (lane >> 5);       \
              ep[x * 257 + (g0 + 0) * 32 + col0] =                              \
                  __fadd_rn(__fmul_rn(__fmul_rn((float)CA[reg], scA.x),         \
                                      scA.y), scA.z);                           \
              ep[x * 257 + (g0 + 1) * 32 + col0] =                              \
                  __fadd_rn(__fmul_rn(__fmul_rn((float)CB[reg], scB.x),         \
                                      scB.y), scB.z);                           \
          }                                                                     \
          __syncthreads();                                                      \
          {                                                                     \
              const int co = tid;                                               \
              const size_t gb = ((size_t)(n * 256 + co)) * 1024                 \
                              + (y0 + (R)) * 32;                                \
              _Pragma("unroll")                                                 \
              for (int x4 = 0; x4 < 32; x4 += 4) {                              \
                  float4 rr;                                                    \
                  rr.x = ep[(x4 + 0) * 257 + co];                               \
                  rr.y = ep[(x4 + 1) * 257 + co];                               \
                  rr.z = ep[(x4 + 2) * 257 + co];                               \
                  rr.w = ep[(x4 + 3) * 257 + co];                               \
                  const float4 xv = *(const float4*)(X + gb + x4);              \
                  rr.x = fminf(1.f, fmaxf(-1.f, __fadd_rn(rr.x, xv.x)));        \
                  rr.y = fminf(1.f, fmaxf(-1.f, __fadd_rn(rr.y, xv.y)));        \
                  rr.z = fminf(1.f, fmaxf(-1.f, __fadd_rn(rr.z, xv.z)));        \
                  rr.w = fminf(1.f, fmaxf(-1.f, __fadd_rn(rr.w, xv.w)));        \
                  *(float4*)(OUT + gb + x4) = rr;                               \
              }                                                                 \
          }                                                                     \
          __syncthreads(); }
        EP2PASS(c0a, c0b, 0)
        EP2PASS(c1a, c1b, 1)
        EP2PASS(c2a, c2b, 2)
        EP2PASS(c3a, c3b, 3)
#undef EP2PASS
    }
}

// ---------------------------------------------------------------------------
extern "C" void kernel_launch(void* const* d_in, const int* in_sizes, int n_in,
                              void* d_out, int out_size, void* d_ws, size_t ws_size,
                              hipStream_t stream)
{
    const float* x   = (const float*)d_in[0];
    const float* w1  = (const float*)d_in[1];
    const float* al1 = (const float*)d_in[2];
    const float* g1  = (const float*)d_in[3];
    const float* b1  = (const float*)d_in[4];
    const float* m1  = (const float*)d_in[5];
    const float* v1  = (const float*)d_in[6];
    const float* w2  = (const float*)d_in[7];
    const float* al2 = (const float*)d_in[8];
    const float* g2  = (const float*)d_in[9];
    const float* b2  = (const float*)d_in[10];
    const float* m2  = (const float*)d_in[11];
    const float* v2  = (const float*)d_in[12];
    float* out = (float*)d_out;

    char* ws = (char*)d_ws;
    float4*        SC4  = (float4*)(ws);                        //   8 KB
    unsigned char* Wsgn = (unsigned char*)(ws + (64u << 10));   // 1.18 MB
    uint4*         Bf   = (uint4*)(ws + (2u << 20));            // 1.18 MB
    u32*           A1   = (u32*)(ws + (4u << 20));              // 2 MB
    u32*           A2   = (u32*)(ws + (6u << 20));              // 2 MB
    (void)ws_size; (void)in_sizes; (void)n_in; (void)out_size;

    prep_weights<<<dim3(256, 2), 256, 0, stream>>>(w1, w2, al1, g1, b1, m1, v1,
                                                   al2, g2, b2, m2, v2, Wsgn, SC4);
    build_bfrag<<<dim3(1152), 64, 0, stream>>>(Wsgn, Bf);
    binarize_x<<<dim3(512), 1024, 0, stream>>>(x, A1);
    conv_mfma<1><<<dim3(512), 256, 0, stream>>>(A1, (const v4i*)Bf, SC4,
                                                nullptr, A2, nullptr);
    conv_mfma<2><<<dim3(512), 256, 0, stream>>>(A2, (const v4i*)Bf, SC4,
                                                x, nullptr, out);
}

// Round 15
// 129.853 us; speedup vs baseline: 1.0724x; 1.0671x over previous
//
#include <hip/hip_runtime.h>
#include <cstdint>
#include <cstddef>

using u32 = unsigned int;
using u64 = unsigned long long;

typedef int v4i  __attribute__((ext_vector_type(4)));
typedef int v16i __attribute__((ext_vector_type(16)));

#define EPSV 1e-5f
#define MFMA_I8(A, B, C) __builtin_amdgcn_mfma_i32_32x32x32_i8((A), (B), (C), 0, 0, 0)

// ---------------------------------------------------------------------------
// Kernel 1: weight prep (unchanged). Wsgn[conv][co][p][c] = sign(w - mean);
// SC4 = (alpha, scale, shift, 0), IEEE ops in the reference's exact order.
// ---------------------------------------------------------------------------
__global__ void prep_weights(const float* __restrict__ w1, const float* __restrict__ w2,
                             const float* __restrict__ a1, const float* __restrict__ g1,
                             const float* __restrict__ b1, const float* __restrict__ m1,
                             const float* __restrict__ v1,
                             const float* __restrict__ a2, const float* __restrict__ g2,
                             const float* __restrict__ b2, const float* __restrict__ m2,
                             const float* __restrict__ v2,
                             unsigned char* __restrict__ Wsgn, float4* __restrict__ SC4)
{
    const int co   = blockIdx.x;
    const int conv = blockIdx.y;
    const int c    = threadIdx.x;
    const float* w = conv ? w2 : w1;

    float wv[9];
    const float* wp = w + ((size_t)co * 256 + c) * 9;
    float s = 0.f;
#pragma unroll
    for (int p = 0; p < 9; ++p) { wv[p] = wp[p]; s += wv[p]; }

    __shared__ float red[256];
    red[c] = s;
    __syncthreads();
    for (int off = 128; off > 0; off >>= 1) {
        if (c < off) red[c] += red[c + off];
        __syncthreads();
    }
    const float mean = __fdiv_rn(red[0], 2304.0f);

    unsigned char* wrow = Wsgn + ((size_t)(conv * 256 + co) * 9) * 256;
#pragma unroll
    for (int p = 0; p < 9; ++p)
        wrow[p * 256 + c] = (wv[p] > mean) ? 0x01u : 0xFFu;

    if (c == 0) {
        const float alpha = conv ? a2[co] : a1[co];
        const float gamma = conv ? g2[co] : g1[co];
        const float beta  = conv ? b2[co] : b1[co];
        const float mu    = conv ? m2[co] : m1[co];
        const float var   = conv ? v2[co] : v1[co];
        const float sq    = __fsqrt_rn(__fadd_rn(var, EPSV));
        const float scale = __fdiv_rn(gamma, sq);
        const float shift = __fsub_rn(beta, __fdiv_rn(__fmul_rn(mu, gamma), sq));
        SC4[conv * 256 + co] = make_float4(alpha, scale, shift, 0.f);
    }
}

// ---------------------------------------------------------------------------
// Kernel 2: B fragments in exact mfma_i32_32x32x32_i8 operand order.
// Frag f = conv*576 + g*72 + k. Lane l: B[k=(l>>5)*16+j][n=l&31].
// ---------------------------------------------------------------------------
__global__ void build_bfrag(const unsigned char* __restrict__ Wsgn, uint4* __restrict__ Bf)
{
    const int f    = blockIdx.x;           // 0..1151
    const int lane = threadIdx.x;          // 0..63
    const int conv = f / 576;
    const int rem  = f % 576;
    const int g    = rem / 72;
    const int p    = (rem % 72) / 8;
    const int cb   = rem % 8;
    const int co   = g * 32 + (lane & 31);
    const unsigned char* src = Wsgn + ((size_t)(conv * 256 + co) * 9 + p) * 256
                                    + cb * 32 + (lane >> 5) * 16;
    Bf[(size_t)f * 64 + lane] = *(const uint4*)src;
}

// ---------------------------------------------------------------------------
// Kernel 3: binarize x -> packed bits. A[n][pixel][j], j = chan/32.
// ---------------------------------------------------------------------------
__global__ void binarize_x(const float* __restrict__ x, u32* __restrict__ A1)
{
    const int n = blockIdx.x >> 3;
    const int j = blockIdx.x & 7;
    const int p = threadIdx.x;
    const float* xp = x + (((size_t)n * 256 + j * 32) * 1024) + p;
    u32 bits = 0;
#pragma unroll
    for (int k = 0; k < 32; ++k) {
        float v = xp[(size_t)k * 1024];
        bits |= (v > 0.f ? 1u : 0u) << k;
    }
    A1[((size_t)n * 1024 + p) * 8 + j] = bits;
}

__device__ __forceinline__ u32 expand4(u32 x)
{
    u32 r;
    r  = ((x & 1u) ? 0x00000001u : 0x000000FFu);
    r |= ((x & 2u) ? 0x00000100u : 0x0000FF00u);
    r |= ((x & 4u) ? 0x00010000u : 0x00FF0000u);
    r |= ((x & 8u) ? 0x01000000u : 0xFF000000u);
    return r;
}

__device__ __forceinline__ void glds16(const void* g, void* l)
{
    __builtin_amdgcn_global_load_lds(
        (const __attribute__((address_space(1))) void*)g,
        (__attribute__((address_space(3))) void*)l, 16, 0, 0);
}

// ---------------------------------------------------------------------------
// Kernel 4/5: binary conv as i8 MFMA GEMM — 8-wave phase schedule (m201 port).
// R5-R14 lesson: every 2-phase stage->compute structure (6 variants) pinned
// at MfmaUtil 20-25% — the documented 2-phase regime ceiling. This version
// ports the verified 8-phase discipline: RAW s_barrier (no vmcnt drain),
// loads issued ONE FULL PHASE before their MFMA, waits always COUNTED:
//   phase k: {2 glds B(k+2) -> buf[k&1]} {4 ds_read A(k+1)}
//            vmcnt(2)+SB  {2 ds_read B(k+1) from buf[(k+1)&1]}
//            s_barrier  lgkmcnt(6)+SB  setprio1  8 MFMA(A(k),B(k))  setprio0
//            s_barrier
// vmcnt counts are per-wave, so each wave stages the B IT CONSUMES (wm=0/1
// duplicate the same bytes — idempotent LDS writes, self-contained counting).
//
// Block: 512 thr = 8 waves; M=256 (8 rows x 32 cols), N=256, 1 block/CU.
// Wave (wm=w>>2, wn=w&3): rows y0+4wm..+3, groups 2wn,2wn+1 -> 8 v16i accs.
// Grid: 64 n x 4 yocts = 256 blocks.
// LDS 103,424 B: A [c16 16][row 10][col 34] 16B cells (87,040; col halo
// stored as zeros -> no edge masking) ; B dbuf at 87,040 (2 x 8,192).
// ds_read addrs: 32 lanes contiguous 512B -> conflict-free (R6-R14: 0).
//
// A: m(=x)=l&31, k=(l>>5)*16+j ; B: n(=co)=l&31 ; C/D: n=l&31,
// m=(reg&3)+8*(reg>>2)+4*(l>>5)   [R5-R14 HW-verified].
//
// CONV==1: t=(dot*alpha)*scale+shift; packed sign bits via __ballot.
// CONV==2: per-row LDS transpose ep[x][co] (pad 257) -> coalesced
//          clamp(t + X) float4 stores.
// ---------------------------------------------------------------------------
template<int CONV>
__global__ __launch_bounds__(512, 2)
void conv_mfma(const u32* __restrict__ A_in, const v4i* __restrict__ Bf,
               const float4* __restrict__ SC4, const float* __restrict__ X,
               u32* __restrict__ A_out, float* __restrict__ OUT)
{
    const int n    = blockIdx.x >> 2;
    const int yo   = blockIdx.x & 3;
    const int y0   = yo * 8;
    const int tid  = threadIdx.x;
    const int wave = tid >> 6;          // 0..7
    const int lane = tid & 63;
    const int wm   = wave >> 2;         // 0/1: rows y0+4wm .. +3
    const int wn   = wave & 3;          // 0..3: groups 2wn, 2wn+1
    const int col0 = lane & 31;
    const int g0   = wn * 2;

    __shared__ alignas(16) unsigned char lds[103424];

    const int fbias = (CONV == 2) ? 576 : 0;
    const char* bsrcA = (const char*)Bf + (((size_t)(fbias + g0 * 72)) << 10)
                        + (size_t)lane * 16;
    const char* bsrcB = bsrcA + (72u << 10);          // group g0+1
    unsigned char* bdst = lds + 87040 + (size_t)g0 * 1024;   // + buf*8192

    // prologue: stage B(0)->buf0, B(1)->buf1 (4 glds; drained by syncthreads)
    glds16(bsrcA,        bdst);
    glds16(bsrcB,        bdst + 1024);
    glds16(bsrcA + 1024, bdst + 8192);
    glds16(bsrcB + 1024, bdst + 8192 + 1024);

    // stage A tile: [c16][row 0..9][col 0..33], halo (row OR col OOB) -> 0
    for (int s = tid; s < 5440; s += 512) {
        const int colv = s % 34;
        const int rest = s / 34;
        const int r    = rest % 10;
        const int c16  = rest / 10;
        const int iy   = y0 - 1 + r;
        const int ix   = colv - 1;
        u32 d0 = 0, d1 = 0, d2 = 0, d3 = 0;
        if ((unsigned)iy < 32u && (unsigned)ix < 32u) {
            const u32 wrd = A_in[((size_t)n * 1024 + iy * 32 + ix) * 8 + (c16 >> 1)];
            const u32 h = (wrd >> ((c16 & 1) * 16)) & 0xFFFFu;
            d0 = expand4(h);
            d1 = expand4(h >> 4);
            d2 = expand4(h >> 8);
            d3 = expand4(h >> 12);
        }
        *(uint4*)(lds + (size_t)s * 16) = make_uint4(d0, d1, d2, d3);
    }

    const int bias2 = (CONV == 2) ? 256 : 0;
    const float4 scA = SC4[bias2 + (g0 + 0) * 32 + col0];
    const float4 scB = SC4[bias2 + (g0 + 1) * 32 + col0];

    __syncthreads();   // A tile visible; ALL prologue vm/lgkm drained

    const v16i Z  = {0,0,0,0,0,0,0,0,0,0,0,0,0,0,0,0};
    v16i c0a = Z, c0b = Z, c1a = Z, c1b = Z;
    v16i c2a = Z, c2b = Z, c3a = Z, c3b = Z;

    const u32 lc16off = (u32)((lane >> 5) * 5440);
    const u32 rowbase = (u32)((4 * wm) * 544);
    const u32 bwoff   = (u32)(g0 * 1024 + lane * 16);

    // preload E set with A(0), B(0)   (k=0: cb=0, dy=0, dx=0)
    v4i ea0, ea1, ea2, ea3, eb0, eb1;
    v4i oa0, oa1, oa2, oa3, ob0, ob1;
    {
        const u32 ao = lc16off + rowbase + (u32)(col0 * 16);
        ea0 = *(const v4i*)(lds + ao);
        ea1 = *(const v4i*)(lds + ao + 544);
        ea2 = *(const v4i*)(lds + ao + 1088);
        ea3 = *(const v4i*)(lds + ao + 1632);
        const u32 bo = 87040u + bwoff;
        eb0 = *(const v4i*)(lds + bo);
        eb1 = *(const v4i*)(lds + bo + 1024);
    }

#define PHASE(KC, AN0, AN1, AN2, AN3, BN0, BN1, AC0, AC1, AC2, AC3, BC0, BC1)   \
    {                                                                           \
        const int k_ = (KC);                                                    \
        int kf_ = k_ + 2; if (kf_ >= 72) kf_ -= 72;                             \
        {                                                                       \
            unsigned char* d_ = bdst + ((k_ & 1) << 13);                        \
            glds16(bsrcA + ((size_t)kf_ << 10), d_);                            \
            glds16(bsrcB + ((size_t)kf_ << 10), d_ + 1024);                     \
        }                                                                       \
        __builtin_amdgcn_sched_barrier(0);                                      \
        {                                                                       \
            const int kn_ = k_ + 1;                                             \
            const int cb_ = kn_ & 7, p_ = kn_ >> 3;                             \
            const int dy_ = p_ / 3, dx_ = p_ - dy_ * 3;                         \
            const u32 ao_ = lc16off + (u32)(2 * cb_) * 5440u + rowbase          \
                          + (u32)(dy_ * 544) + (u32)((dx_ + col0) * 16);        \
            AN0 = *(const v4i*)(lds + ao_);                                     \
            AN1 = *(const v4i*)(lds + ao_ + 544);                               \
            AN2 = *(const v4i*)(lds + ao_ + 1088);                              \
            AN3 = *(const v4i*)(lds + ao_ + 1632);                              \
            asm volatile("s_waitcnt vmcnt(2)" ::: "memory");                    \
            __builtin_amdgcn_sched_barrier(0);                                  \
            const u32 bo_ = 87040u + (u32)((kn_ & 1) << 13) + bwoff;            \
            BN0 = *(const v4i*)(lds + bo_);                                     \
            BN1 = *(const v4i*)(lds + bo_ + 1024);                              \
        }                                                                       \
        __builtin_amdgcn_s_barrier();                                           \
        asm volatile("s_waitcnt lgkmcnt(6)" ::: "memory");                      \
        __builtin_amdgcn_sched_barrier(0);                                      \
        __builtin_amdgcn_s_setprio(1);                                          \
        c0a = MFMA_I8(AC0, BC0, c0a);  c0b = MFMA_I8(AC0, BC1, c0b);            \
        c1a = MFMA_I8(AC1, BC0, c1a);  c1b = MFMA_I8(AC1, BC1, c1b);            \
        c2a = MFMA_I8(AC2, BC0, c2a);  c2b = MFMA_I8(AC2, BC1, c2b);            \
        c3a = MFMA_I8(AC3, BC0, c3a);  c3b = MFMA_I8(AC3, BC1, c3b);            \
        __builtin_amdgcn_s_setprio(0);                                          \
        __builtin_amdgcn_s_barrier();                                           \
    }

#pragma unroll 1
    for (int j = 0; j < 36; ++j) {
        const int k = j * 2;
        PHASE(k,     oa0, oa1, oa2, oa3, ob0, ob1,  ea0, ea1, ea2, ea3, eb0, eb1)
        PHASE(k + 1, ea0, ea1, ea2, ea3, eb0, eb1,  oa0, oa1, oa2, oa3, ob0, ob1)
    }
#undef PHASE

    if (CONV == 1) {
#define EP1(ACC, MR, GI, SC)                                                    \
        { _Pragma("unroll")                                                     \
          for (int reg = 0; reg < 16; ++reg) {                                  \
              const float t = __fadd_rn(__fmul_rn(__fmul_rn((float)ACC[reg],    \
                                        SC.x), SC.y), SC.z);                    \
              const u64 m = __ballot(t > 0.f);                                  \
              if (lane == 0) {                                                  \
                  const int x = (reg & 3) + 8 * (reg >> 2);                     \
                  const int row = y0 + 4 * wm + (MR);                           \
                  const size_t pb = (size_t)n * 1024 + row * 32 + x;            \
                  A_out[pb * 8 + (g0 + (GI))]       = (u32)m;                   \
                  A_out[(pb + 4) * 8 + (g0 + (GI))] = (u32)(m >> 32);           \
              } } }
        EP1(c0a, 0, 0, scA)  EP1(c0b, 0, 1, scB)
        EP1(c1a, 1, 0, scA)  EP1(c1b, 1, 1, scB)
        EP1(c2a, 2, 0, scA)  EP1(c2b, 2, 1, scB)
        EP1(c3a, 3, 0, scA)  EP1(c3b, 3, 1, scB)
#undef EP1
    } else {
        __syncthreads();
        float* ep = (float*)lds;            // ep[x][co], stride 257 (32.9 KB)
#define EP2PASS(CA, CB, R)                                                      \
        { if (wm == ((R) >> 2)) {                                               \
            _Pragma("unroll")                                                   \
            for (int reg = 0; reg < 16; ++reg) {                                \
                const int x = (reg & 3) + 8 * (reg >> 2) + 4 * (lane >> 5);     \
                ep[x * 257 + (g0 + 0) * 32 + col0] =                            \
                    __fadd_rn(__fmul_rn(__fmul_rn((float)CA[reg], scA.x),       \
                                        scA.y), scA.z);                         \
                ep[x * 257 + (g0 + 1) * 32 + col0] =                            \
                    __fadd_rn(__fmul_rn(__fmul_rn((float)CB[reg], scB.x),       \
                                        scB.y), scB.z);                         \
            } }                                                                 \
          __syncthreads();                                                      \
          {                                                                     \
              const int co = tid >> 1, xh = tid & 1;                            \
              const size_t gb = ((size_t)(n * 256 + co)) * 1024                 \
                              + (y0 + (R)) * 32 + xh * 16;                      \
              _Pragma("unroll")                                                 \
              for (int x4 = 0; x4 < 16; x4 += 4) {                              \
                  float4 rr;                                                    \
                  rr.x = ep[(xh * 16 + x4 + 0) * 257 + co];                     \
                  rr.y = ep[(xh * 16 + x4 + 1) * 257 + co];                     \
                  rr.z = ep[(xh * 16 + x4 + 2) * 257 + co];                     \
                  rr.w = ep[(xh * 16 + x4 + 3) * 257 + co];                     \
                  const float4 xv = *(const float4*)(X + gb + x4);              \
                  rr.x = fminf(1.f, fmaxf(-1.f, __fadd_rn(rr.x, xv.x)));        \
                  rr.y = fminf(1.f, fmaxf(-1.f, __fadd_rn(rr.y, xv.y)));        \
                  rr.z = fminf(1.f, fmaxf(-1.f, __fadd_rn(rr.z, xv.z)));        \
                  rr.w = fminf(1.f, fmaxf(-1.f, __fadd_rn(rr.w, xv.w)));        \
                  *(float4*)(OUT + gb + x4) = rr;                               \
              }                                                                 \
          }                                                                     \
          __syncthreads(); }
        EP2PASS(c0a, c0b, 0)
        EP2PASS(c1a, c1b, 1)
        EP2PASS(c2a, c2b, 2)
        EP2PASS(c3a, c3b, 3)
        EP2PASS(c0a, c0b, 4)
        EP2PASS(c1a, c1b, 5)
        EP2PASS(c2a, c2b, 6)
        EP2PASS(c3a, c3b, 7)
#undef EP2PASS
    }
}

// ---------------------------------------------------------------------------
extern "C" void kernel_launch(void* const* d_in, const int* in_sizes, int n_in,
                              void* d_out, int out_size, void* d_ws, size_t ws_size,
                              hipStream_t stream)
{
    const float* x   = (const float*)d_in[0];
    const float* w1  = (const float*)d_in[1];
    const float* al1 = (const float*)d_in[2];
    const float* g1  = (const float*)d_in[3];
    const float* b1  = (const float*)d_in[4];
    const float* m1  = (const float*)d_in[5];
    const float* v1  = (const float*)d_in[6];
    const float* w2  = (const float*)d_in[7];
    const float* al2 = (const float*)d_in[8];
    const float* g2  = (const float*)d_in[9];
    const float* b2  = (const float*)d_in[10];
    const float* m2  = (const float*)d_in[11];
    const float* v2  = (const float*)d_in[12];
    float* out = (float*)d_out;

    char* ws = (char*)d_ws;
    float4*        SC4  = (float4*)(ws);                        //   8 KB
    unsigned char* Wsgn = (unsigned char*)(ws + (64u << 10));   // 1.18 MB
    uint4*         Bf   = (uint4*)(ws + (2u << 20));            // 1.18 MB
    u32*           A1   = (u32*)(ws + (4u << 20));              // 2 MB
    u32*           A2   = (u32*)(ws + (6u << 20));              // 2 MB
    (void)ws_size; (void)in_sizes; (void)n_in; (void)out_size;

    prep_weights<<<dim3(256, 2), 256, 0, stream>>>(w1, w2, al1, g1, b1, m1, v1,
                                                   al2, g2, b2, m2, v2, Wsgn, SC4);
    build_bfrag<<<dim3(1152), 64, 0, stream>>>(Wsgn, Bf);
    binarize_x<<<dim3(512), 1024, 0, stream>>>(x, A1);
    conv_mfma<1><<<dim3(256), 512, 0, stream>>>(A1, (const v4i*)Bf, SC4,
                                                nullptr, A2, nullptr);
    conv_mfma<2><<<dim3(256), 512, 0, stream>>>(A2, (const v4i*)Bf, SC4,
                                                x, nullptr, out);
}